// Round 12
// baseline (30.433 us; speedup 1.0000x reference)
//
#include <hip/hip_runtime.h>

// CustomBatchNorm2D forward — single pass over x, 2 channels per block,
// R9 structure (best measured: 24.7 µs) + micro-tweaks.
//
// x (N=32, C=512, H=32, W=32) f32.
//   S[i,c]  = sum_hw x[i,c,:]
//   mean[c] = sum_i S[i,c] / (N*HW)
//   diag[c] = sum_i (S[i,c] - HW*mean[c])^2 / HW
//   out     = A[c]*x + B[c],  A = gamma[c]*abs(diag[c]),  B = beta[c] - A*mean[c]
//
// Schedule (per block): issue all 16 loads -> staircase-reduce c0 ->
// LDS-only barrier -> stats0 -> store c0 (c1 loads still landing) ->
// staircase-reduce c1 -> LDS-only barrier -> stats1 -> store c1.
// Plateau evidence (R9/R10/R11: 24.7/25.6/25.1) says we sit at the
// mixed-stream HBM ceiling (~6.3 TB/s on 134 MB = 21.3 µs) + ~3 µs
// launch/barrier overhead. Tweaks here: plain loads (keep nt stores only),
// to let L2 buffer the read stream.
//
// Grid: 256 blocks x 1024 threads = 1 block/CU. Thread map: row r = t>>5
// (32 lanes per row), float4 slots j + 32k, k=0..7. Channels c0=b, c1=b+256.

#define HW_   1024
#define C_    512
#define N_    32

typedef float f4 __attribute__((ext_vector_type(4)));

__global__ void __launch_bounds__(1024)
bn_pipe5(const float* __restrict__ x,
         const float* __restrict__ gamma,
         const float* __restrict__ beta,
         float* __restrict__ out) {
    const int t  = threadIdx.x;
    const int r  = t >> 5;          // sample/row 0..31
    const int j  = t & 31;          // float4 slot base within row
    const int c0 = blockIdx.x;
    const int c1 = c0 + 256;

    const f4* xv = reinterpret_cast<const f4*>(x);
    f4*       ov = reinterpret_cast<f4*>(out);
    const size_t base0 = (((size_t)(r * C_ + c0)) << 8) + j;
    const size_t base1 = (((size_t)(r * C_ + c1)) << 8) + j;

    __shared__ float Sl0[N_], Sl1[N_];

    // ---- issue ALL loads up front: continuous chip-wide read stream ----
    f4 d0[8], d1[8];
    #pragma unroll
    for (int k = 0; k < 8; ++k)
        d0[k] = xv[base0 + k * 32];
    #pragma unroll
    for (int k = 0; k < 8; ++k)
        d1[k] = xv[base1 + k * 32];
    __builtin_amdgcn_sched_barrier(0);   // keep the 16-load cluster here

    // ---- staircase reduce c0 (consume loads as they land) ----
    {
        float s = 0.f;
        #pragma unroll
        for (int k = 0; k < 8; ++k)
            s += (d0[k].x + d0[k].y) + (d0[k].z + d0[k].w);
        #pragma unroll
        for (int off = 16; off > 0; off >>= 1)
            s += __shfl_xor(s, off, 64);     // stays within the 32-lane group
        if (j == 0) Sl0[r] = s;
    }
    // pin AFTER reduce (waits satisfied): blocks rematerialization only
    #pragma unroll
    for (int k = 0; k < 8; ++k)
        asm volatile("" : "+v"(d0[k]));

    // ---- LDS-only barrier: does NOT drain vmcnt (d1 stays in flight) ----
    asm volatile("s_waitcnt lgkmcnt(0)" ::: "memory");
    __builtin_amdgcn_s_barrier();

    // ---- stats c0 (redundant per thread; uniform LDS broadcasts) ----
    float A0, B0;
    {
        float tot = 0.f;
        #pragma unroll
        for (int i = 0; i < N_; ++i) tot += Sl0[i];
        const float mean  = tot * (1.0f / (float)(N_ * HW_));
        const float m1024 = tot * (1.0f / (float)N_);
        float dd = 0.f;
        #pragma unroll
        for (int i = 0; i < N_; ++i) {
            const float e = Sl0[i] - m1024;
            dd += e * e;
        }
        const float diag = dd * (1.0f / (float)HW_);
        A0 = gamma[c0] * fabsf(diag);
        B0 = beta[c0] - A0 * mean;
    }

    // ---- store c0 (c1 reads still streaming underneath) ----
    #pragma unroll
    for (int k = 0; k < 8; ++k) {
        f4 o;
        o.x = fmaf(A0, d0[k].x, B0);
        o.y = fmaf(A0, d0[k].y, B0);
        o.z = fmaf(A0, d0[k].z, B0);
        o.w = fmaf(A0, d0[k].w, B0);
        __builtin_nontemporal_store(o, ov + base0 + k * 32);
    }

    // ---- staircase reduce c1 (mostly landed by now) ----
    {
        float s = 0.f;
        #pragma unroll
        for (int k = 0; k < 8; ++k)
            s += (d1[k].x + d1[k].y) + (d1[k].z + d1[k].w);
        #pragma unroll
        for (int off = 16; off > 0; off >>= 1)
            s += __shfl_xor(s, off, 64);
        if (j == 0) Sl1[r] = s;
    }
    #pragma unroll
    for (int k = 0; k < 8; ++k)
        asm volatile("" : "+v"(d1[k]));

    asm volatile("s_waitcnt lgkmcnt(0)" ::: "memory");
    __builtin_amdgcn_s_barrier();

    // ---- stats c1 ----
    float A1, B1;
    {
        float tot = 0.f;
        #pragma unroll
        for (int i = 0; i < N_; ++i) tot += Sl1[i];
        const float mean  = tot * (1.0f / (float)(N_ * HW_));
        const float m1024 = tot * (1.0f / (float)N_);
        float dd = 0.f;
        #pragma unroll
        for (int i = 0; i < N_; ++i) {
            const float e = Sl1[i] - m1024;
            dd += e * e;
        }
        const float diag = dd * (1.0f / (float)HW_);
        A1 = gamma[c1] * fabsf(diag);
        B1 = beta[c1] - A1 * mean;
    }

    // ---- store c1 ----
    #pragma unroll
    for (int k = 0; k < 8; ++k) {
        f4 o;
        o.x = fmaf(A1, d1[k].x, B1);
        o.y = fmaf(A1, d1[k].y, B1);
        o.z = fmaf(A1, d1[k].z, B1);
        o.w = fmaf(A1, d1[k].w, B1);
        __builtin_nontemporal_store(o, ov + base1 + k * 32);
    }
}

extern "C" void kernel_launch(void* const* d_in, const int* in_sizes, int n_in,
                              void* d_out, int out_size, void* d_ws, size_t ws_size,
                              hipStream_t stream) {
    const float* x     = (const float*)d_in[0];
    const float* gamma = (const float*)d_in[1];
    const float* beta  = (const float*)d_in[2];
    float*       out   = (float*)d_out;

    bn_pipe5<<<256, 1024, 0, stream>>>(x, gamma, beta, out);
    (void)in_sizes; (void)n_in; (void)out_size; (void)d_ws; (void)ws_size;
}

// Round 13
// 24.239 us; speedup vs baseline: 1.2555x; 1.2555x over previous
//
#include <hip/hip_runtime.h>

// CustomBatchNorm2D forward — single pass over x, 2 channels per block.
// EXACT restore of the round-9 kernel (best measured: 24.745 µs).
//
// Round-12 A/B result: removing __builtin_nontemporal_load cost +5.4 µs
// (24.7 -> 30.4). nt on BOTH loads and stores is required: plain loads
// allocate the 64 MiB read stream into L2 and thrash against the store
// stream. Do not remove nt again.
//
// x (N=32, C=512, H=32, W=32) f32.
//   S[i,c]  = sum_hw x[i,c,:]
//   mean[c] = sum_i S[i,c] / (N*HW)
//   diag[c] = sum_i (S[i,c] - HW*mean[c])^2 / HW
//   out     = A[c]*x + B[c],  A = gamma[c]*abs(diag[c]),  B = beta[c] - A*mean[c]
//
// Grid: 256 blocks x 1024 threads = 1 block/CU. Thread map: row r = t>>5
// (32 lanes per row), float4 slots j + 32k, k=0..7. Channels c0=b, c1=b+256.

#define HW_   1024
#define C_    512
#define N_    32

typedef float f4 __attribute__((ext_vector_type(4)));

__global__ void __launch_bounds__(1024)
bn_pipe3r(const float* __restrict__ x,
          const float* __restrict__ gamma,
          const float* __restrict__ beta,
          float* __restrict__ out) {
    const int t  = threadIdx.x;
    const int r  = t >> 5;          // sample/row 0..31
    const int j  = t & 31;          // float4 slot base within row
    const int c0 = blockIdx.x;
    const int c1 = c0 + 256;

    const f4* xv = reinterpret_cast<const f4*>(x);
    f4*       ov = reinterpret_cast<f4*>(out);
    const size_t base0 = (((size_t)(r * C_ + c0)) << 8) + j;
    const size_t base1 = (((size_t)(r * C_ + c1)) << 8) + j;

    __shared__ float Sl0[N_], Sl1[N_];

    // ---- issue ALL loads up front: continuous chip-wide read stream ----
    f4 d0[8], d1[8];
    #pragma unroll
    for (int k = 0; k < 8; ++k)
        d0[k] = __builtin_nontemporal_load(xv + base0 + k * 32);
    #pragma unroll
    for (int k = 0; k < 8; ++k)
        d1[k] = __builtin_nontemporal_load(xv + base1 + k * 32);
    __builtin_amdgcn_sched_barrier(0);   // keep the load cluster here

    // pin d0 (counted waits; also blocks rematerialization of the loads)
    #pragma unroll
    for (int k = 0; k < 8; ++k)
        asm volatile("" : "+v"(d0[k]));

    // ---- reduce c0: per-thread sum, 32-lane-group butterfly ----
    {
        float s = 0.f;
        #pragma unroll
        for (int k = 0; k < 8; ++k)
            s += (d0[k].x + d0[k].y) + (d0[k].z + d0[k].w);
        #pragma unroll
        for (int off = 16; off > 0; off >>= 1)
            s += __shfl_xor(s, off, 64);     // stays within the 32-lane group
        if (j == 0) Sl0[r] = s;
    }

    // ---- LDS-only barrier: does NOT drain vmcnt (d1 stays in flight) ----
    asm volatile("s_waitcnt lgkmcnt(0)" ::: "memory");
    __builtin_amdgcn_s_barrier();

    // ---- stats c0 (redundant per thread; uniform LDS broadcasts) ----
    float A0, B0;
    {
        float tot = 0.f;
        #pragma unroll
        for (int i = 0; i < N_; ++i) tot += Sl0[i];
        const float mean  = tot * (1.0f / (float)(N_ * HW_));
        const float m1024 = tot * (1.0f / (float)N_);
        float dd = 0.f;
        #pragma unroll
        for (int i = 0; i < N_; ++i) {
            const float e = Sl0[i] - m1024;
            dd += e * e;
        }
        const float diag = dd * (1.0f / (float)HW_);
        A0 = gamma[c0] * fabsf(diag);
        B0 = beta[c0] - A0 * mean;
    }

    // ---- store c0 (c1 reads still streaming underneath) ----
    #pragma unroll
    for (int k = 0; k < 8; ++k) {
        f4 o;
        o.x = fmaf(A0, d0[k].x, B0);
        o.y = fmaf(A0, d0[k].y, B0);
        o.z = fmaf(A0, d0[k].z, B0);
        o.w = fmaf(A0, d0[k].w, B0);
        __builtin_nontemporal_store(o, ov + base0 + k * 32);
    }

    // ---- NOW consume d1 (counted vmcnt waits; most data already landed) ----
    #pragma unroll
    for (int k = 0; k < 8; ++k)
        asm volatile("" : "+v"(d1[k]));

    // ---- reduce c1 ----
    {
        float s = 0.f;
        #pragma unroll
        for (int k = 0; k < 8; ++k)
            s += (d1[k].x + d1[k].y) + (d1[k].z + d1[k].w);
        #pragma unroll
        for (int off = 16; off > 0; off >>= 1)
            s += __shfl_xor(s, off, 64);
        if (j == 0) Sl1[r] = s;
    }

    asm volatile("s_waitcnt lgkmcnt(0)" ::: "memory");
    __builtin_amdgcn_s_barrier();

    // ---- stats c1 ----
    float A1, B1;
    {
        float tot = 0.f;
        #pragma unroll
        for (int i = 0; i < N_; ++i) tot += Sl1[i];
        const float mean  = tot * (1.0f / (float)(N_ * HW_));
        const float m1024 = tot * (1.0f / (float)N_);
        float dd = 0.f;
        #pragma unroll
        for (int i = 0; i < N_; ++i) {
            const float e = Sl1[i] - m1024;
            dd += e * e;
        }
        const float diag = dd * (1.0f / (float)HW_);
        A1 = gamma[c1] * fabsf(diag);
        B1 = beta[c1] - A1 * mean;
    }

    // ---- store c1 ----
    #pragma unroll
    for (int k = 0; k < 8; ++k) {
        f4 o;
        o.x = fmaf(A1, d1[k].x, B1);
        o.y = fmaf(A1, d1[k].y, B1);
        o.z = fmaf(A1, d1[k].z, B1);
        o.w = fmaf(A1, d1[k].w, B1);
        __builtin_nontemporal_store(o, ov + base1 + k * 32);
    }
}

extern "C" void kernel_launch(void* const* d_in, const int* in_sizes, int n_in,
                              void* d_out, int out_size, void* d_ws, size_t ws_size,
                              hipStream_t stream) {
    const float* x     = (const float*)d_in[0];
    const float* gamma = (const float*)d_in[1];
    const float* beta  = (const float*)d_in[2];
    float*       out   = (float*)d_out;

    bn_pipe3r<<<256, 1024, 0, stream>>>(x, gamma, beta, out);
    (void)in_sizes; (void)n_in; (void)out_size; (void)d_ws; (void)ws_size;
}